// Round 13
// baseline (453.479 us; speedup 1.0000x reference)
//
#include <hip/hip_runtime.h>
#include <math.h>
#include <stdint.h>

#define N_NODES 32768
#define E_DIM   512
#define H_HEADS 8
#define D_HEAD  64
#define NNZ_E   524288

typedef __attribute__((ext_vector_type(4))) float f32x4;
typedef __attribute__((ext_vector_type(8))) short bf16x8;  // 8 bf16 = 4 VGPRs
typedef __attribute__((ext_vector_type(8))) short s16x8;

__device__ __forceinline__ unsigned short f32_to_bf16_rne(float f) {
  union { float f; uint32_t u; } v; v.f = f;
  const uint32_t u = v.u;
  return (unsigned short)((u + 0x7FFFu + ((u >> 16) & 1u)) >> 16);
}
__device__ __forceinline__ float bf16_to_f32(unsigned short h) {
  union { uint32_t u; float f; } v; v.u = ((uint32_t)h) << 16;
  return v.f;
}

// split pair (a,b) fp32 -> packed bf16 hi dword + packed bf16 lo dword.
__device__ __forceinline__ void split2(float a, float b,
                                       uint32_t& hi, uint32_t& lo) {
  const uint32_t ua = __float_as_uint(a), ub = __float_as_uint(b);
  hi = __builtin_amdgcn_perm(ub, ua, 0x07060302u);  // [b.hi16 : a.hi16]
  const float ra = a - __uint_as_float(ua & 0xFFFF0000u);
  const float rb = b - __uint_as_float(ub & 0xFFFF0000u);
  lo = __builtin_amdgcn_perm(__float_as_uint(rb), __float_as_uint(ra),
                             0x07060302u);
}

// ---------------------------------------------------------------------------
// prep_small: blocks 0..511 -> cvt_w (split q_w/k_w into bf16 hi|lo);
//             blocks 512..2559 -> build_aux (ge + CSR row_start).
// ---------------------------------------------------------------------------
__global__ __launch_bounds__(256) void prep_small(
    const float* __restrict__ q_w, const float* __restrict__ k_w,
    const int* __restrict__ row_index, const int* __restrict__ col_index,
    const int* __restrict__ to_col,
    unsigned short* __restrict__ wq_s, unsigned short* __restrict__ wk_s,
    int* __restrict__ row_start, int* __restrict__ ge) {
  const int b = blockIdx.x;
  if (b < 512) {
    const float* src = (b < 256) ? q_w : k_w;
    unsigned short* dst = (b < 256) ? wq_s : wk_s;
    const int t = (b & 255) * 256 + threadIdx.x;
    const int r = t >> 7;
    const int c4 = (t & 127) << 2;
    const float4 v = *(const float4*)(src + (size_t)r * 512 + c4);
    ushort4 hi, lo;
    hi.x = f32_to_bf16_rne(v.x); lo.x = f32_to_bf16_rne(v.x - bf16_to_f32(hi.x));
    hi.y = f32_to_bf16_rne(v.y); lo.y = f32_to_bf16_rne(v.y - bf16_to_f32(hi.y));
    hi.z = f32_to_bf16_rne(v.z); lo.z = f32_to_bf16_rne(v.z - bf16_to_f32(hi.z));
    hi.w = f32_to_bf16_rne(v.w); lo.w = f32_to_bf16_rne(v.w - bf16_to_f32(hi.w));
    *(ushort4*)(dst + (size_t)r * 1024 + c4) = hi;
    *(ushort4*)(dst + (size_t)r * 1024 + 512 + c4) = lo;
  } else {
    const int e = (b - 512) * 256 + threadIdx.x;
    if (e < NNZ_E) {
      ge[e] = to_col[col_index[e]];
      const int r0 = row_index[e];
      const int r1 = (e + 1 < NNZ_E) ? row_index[e + 1] : N_NODES;
      if (e == 0)
        for (int r = 0; r <= r0; ++r) row_start[r] = 0;
      for (int r = r0 + 1; r <= r1; ++r) row_start[r] = e + 1;
    }
  }
}

// ---------------------------------------------------------------------------
// LDS-FREE split-bf16 MFMA GEMM. r12's PMC showed the LDS pipe was the
// bottleneck (16 ds_read_b128/wave-k0 -> 6 waves x 192 cyc = 1150 cyc of
// LDS demand vs 350 cyc MFMA -> MfmaUtil 31%). Fragments for 16x16x32 are
// 8 consecutive k-elements per lane, so both operands load DIRECTLY from
// global to registers (A: 2x dwordx4 fp32, split hi/lo in-register; B:
// hi+lo dwordx4 from the pre-split weights). No LDS, no barriers -- the
// K-loop is a pure load/MFMA stream with compiler-scheduled vmcnt. Reuse
// lives in L2 (A: ~1 GB L2-reads ~ 11 TB/s << 35 ceiling; B: 2 MB hot).
// XCD swizzle (b&7 = panel group) keeps A HBM-once as measured in r12.
// Outputs int16: q16 = q*16384, k16 = k*4096.
// ---------------------------------------------------------------------------
__global__ __launch_bounds__(256) void gemm_mfma(
    const float* __restrict__ x,             // [N][512] fp32
    const unsigned short* __restrict__ wqs,  // [512][1024] hi|lo
    const unsigned short* __restrict__ wks,
    const float* __restrict__ q_b, const float* __restrict__ k_b,
    short* __restrict__ q16, short* __restrict__ k16) {
  const int tid = threadIdx.x;
  const int w = tid >> 6;        // wave 0..3
  const int l = tid & 63;

  const int b = blockIdx.x;
  const int j = b >> 3;
  const int mb = (b & 7) * 32 + (j >> 3);
  const int c = j & 7;
  const bool is_q = ((c & 1) == 0);
  const int bm = mb * 128;
  const int bn = (c >> 1) * 128;

  const unsigned short* __restrict__ wmat = is_q ? wqs : wks;
  const float* __restrict__ bias = is_q ? q_b : k_b;
  short* __restrict__ outp = is_q ? q16 : k16;
  const float oscale = is_q ? 2048.f : 4096.f;

  const int wm = (w & 1) * 64;   // wave's m-quadrant
  const int wn = (w >> 1) * 64;  // wave's n-quadrant

  f32x4 acc[4][4];
#pragma unroll
  for (int i = 0; i < 4; ++i)
#pragma unroll
    for (int jj = 0; jj < 4; ++jj) acc[i][jj] = (f32x4){0.f, 0.f, 0.f, 0.f};

  // fragment address bases: lane l -> row offset fr = l&15, k offset
  // kc = (l>>4)*8 (8 consecutive elements -> one dwordx4 pair / dwordx4)
  const int fr = l & 15;
  const int kc = (l >> 4) * 8;

  const float* __restrict__ xa0 = x + (size_t)(bm + wm + fr) * 512 + kc;
  const unsigned short* __restrict__ wb0 =
      wmat + (size_t)(bn + wn + fr) * 1024 + kc;

  for (int k0 = 0; k0 < 512; k0 += 32) {
    // ---- load all fragments (16 x dwordx4, no barrier, vmcnt-scheduled)
    float4 fa[4], fb[4];
    bf16x8 bh[4], bl[4];
#pragma unroll
    for (int i = 0; i < 4; ++i) {
      const float* rp = xa0 + (size_t)(i * 16) * 512 + k0;
      fa[i] = *(const float4*)rp;
      fb[i] = *(const float4*)(rp + 4);
    }
#pragma unroll
    for (int i = 0; i < 4; ++i) {
      const unsigned short* bp = wb0 + (size_t)(i * 16) * 1024 + k0;
      bh[i] = *(const bf16x8*)bp;
      bl[i] = *(const bf16x8*)(bp + 512);
    }
    // ---- split A to bf16 hi/lo in-register
    bf16x8 ahi[4], alo[4];
#pragma unroll
    for (int i = 0; i < 4; ++i) {
      union { uint32_t u[4]; bf16x8 v; } ph, pl;
      split2(fa[i].x, fa[i].y, ph.u[0], pl.u[0]);
      split2(fa[i].z, fa[i].w, ph.u[1], pl.u[1]);
      split2(fb[i].x, fb[i].y, ph.u[2], pl.u[2]);
      split2(fb[i].z, fb[i].w, ph.u[3], pl.u[3]);
      ahi[i] = ph.v;
      alo[i] = pl.v;
    }
    // ---- 3 terms x 16 MFMA
#pragma unroll
    for (int i = 0; i < 4; ++i)
#pragma unroll
      for (int jj = 0; jj < 4; ++jj)
        acc[i][jj] = __builtin_amdgcn_mfma_f32_16x16x32_bf16(
            ahi[i], bh[jj], acc[i][jj], 0, 0, 0);
#pragma unroll
    for (int i = 0; i < 4; ++i)
#pragma unroll
      for (int jj = 0; jj < 4; ++jj)
        acc[i][jj] = __builtin_amdgcn_mfma_f32_16x16x32_bf16(
            alo[i], bh[jj], acc[i][jj], 0, 0, 0);
#pragma unroll
    for (int i = 0; i < 4; ++i)
#pragma unroll
      for (int jj = 0; jj < 4; ++jj)
        acc[i][jj] = __builtin_amdgcn_mfma_f32_16x16x32_bf16(
            ahi[i], bl[jj], acc[i][jj], 0, 0, 0);
  }

  // epilogue: C/D layout col = l&15 (n), row = (l>>4)*4 + reg (m); int16 out
  const int cn = l & 15;
  const int cm4 = (l >> 4) * 4;
  float bvals[4];
#pragma unroll
  for (int jj = 0; jj < 4; ++jj) bvals[jj] = bias[bn + wn + jj * 16 + cn];
#pragma unroll
  for (int i = 0; i < 4; ++i) {
#pragma unroll
    for (int r = 0; r < 4; ++r) {
      const int m = bm + wm + i * 16 + cm4 + r;
      short* op = outp + (size_t)m * 512 + bn + wn + cn;
#pragma unroll
      for (int jj = 0; jj < 4; ++jj) {
        float v = (acc[i][jj][r] + bvals[jj]) * oscale;
        v = fmaxf(fminf(v, 32767.f), -32767.f);
        op[jj * 16] = (short)__float2int_rn(v);
      }
    }
  }
}

// ---------------------------------------------------------------------------
// Phase A: 4 edges per wave, batched loads; q AND k gathered as int16.
// logit = (sum q16*k16) / 2^26 + bias.
// ---------------------------------------------------------------------------
__global__ __launch_bounds__(256) void edge_logits(
    const short* __restrict__ q16, const short* __restrict__ k16,
    const int* __restrict__ row_index, const int* __restrict__ ge,
    const float* __restrict__ att_bias, float* __restrict__ logits) {
  const int wave = threadIdx.x >> 6;
  const int lane = threadIdx.x & 63;
  const int e0 = __builtin_amdgcn_readfirstlane((blockIdx.x * 4 + wave) * 4);

  int r[4], g[4];
#pragma unroll
  for (int i = 0; i < 4; ++i) {
    r[i] = row_index[e0 + i];
    g[i] = ge[e0 + i];
  }

  const int lo = lane * 8;
  s16x8 kv[4], qv[4];
#pragma unroll
  for (int i = 0; i < 4; ++i)
    kv[i] = *(const s16x8*)(k16 + (size_t)g[i] * E_DIM + lo);
#pragma unroll
  for (int i = 0; i < 4; ++i)
    qv[i] = *(const s16x8*)(q16 + (size_t)r[i] * E_DIM + lo);

  const int h = lane >> 3;
#pragma unroll
  for (int i = 0; i < 4; ++i) {
    float s = (float)qv[i][0] * (float)kv[i][0];
    s = fmaf((float)qv[i][1], (float)kv[i][1], s);
    s = fmaf((float)qv[i][2], (float)kv[i][2], s);
    s = fmaf((float)qv[i][3], (float)kv[i][3], s);
    s = fmaf((float)qv[i][4], (float)kv[i][4], s);
    s = fmaf((float)qv[i][5], (float)kv[i][5], s);
    s = fmaf((float)qv[i][6], (float)kv[i][6], s);
    s = fmaf((float)qv[i][7], (float)kv[i][7], s);
    s += __shfl_xor(s, 1);
    s += __shfl_xor(s, 2);
    s += __shfl_xor(s, 4);
    if ((lane & 7) == 0) {
      logits[(size_t)(e0 + i) * H_HEADS + h] =
          s * (1.f / 67108864.f) + att_bias[(size_t)h * NNZ_E + e0 + i];
    }
  }
}

// ---------------------------------------------------------------------------
// Phase B: 4 rows per block (1 wave per row); lane (h,j) strided
// online-softmax + 3-step merge.
// ---------------------------------------------------------------------------
__global__ __launch_bounds__(256) void row_featurize(
    const float* __restrict__ logits, const int* __restrict__ row_start,
    const int* __restrict__ col_index, const float* __restrict__ dist,
    const float* __restrict__ pos, const float* __restrict__ col_pos,
    float* __restrict__ out) {
  const int r = blockIdx.x * 4 + (threadIdx.x >> 6);
  const int lane = threadIdx.x & 63;
  const int h = lane >> 3;
  const int j = lane & 7;
  const int start = row_start[r];
  const int end = row_start[r + 1];

  float m = -INFINITY, l = 0.f, accw = 0.f, a0 = 0.f, a1 = 0.f, a2 = 0.f;

  for (int e = start + j; e < end; e += 8) {
    const float s = logits[(size_t)e * H_HEADS + h];
    const float dd = dist[e];
    const float w = (dd == 0.f) ? 0.f : 1.f / dd;
    const int c = col_index[e];
    const float nm = fmaxf(m, s);
    const float sc = __expf(m - nm);
    const float p = __expf(s - nm);
    m = nm;
    l = fmaf(l, sc, p);
    const float pw = p * w;
    accw = fmaf(accw, sc, pw);
    a0 = fmaf(a0, sc, pw * col_pos[c * 3 + 0]);
    a1 = fmaf(a1, sc, pw * col_pos[c * 3 + 1]);
    a2 = fmaf(a2, sc, pw * col_pos[c * 3 + 2]);
  }

#pragma unroll
  for (int off = 1; off < 8; off <<= 1) {
    const float mo = __shfl_xor(m, off);
    const float lo = __shfl_xor(l, off);
    const float wo = __shfl_xor(accw, off);
    const float b0 = __shfl_xor(a0, off);
    const float b1 = __shfl_xor(a1, off);
    const float b2 = __shfl_xor(a2, off);
    const float nm = fmaxf(m, mo);
    const float s1 = __expf(fmaxf(m - nm, -80.f));  // NaN (inf-inf) -> -80
    const float s2 = __expf(fmaxf(mo - nm, -80.f));
    m = nm;
    l = l * s1 + lo * s2;
    accw = accw * s1 + wo * s2;
    a0 = a0 * s1 + b0 * s2;
    a1 = a1 * s1 + b1 * s2;
    a2 = a2 * s1 + b2 * s2;
  }

  if (j == 0) {
    const float invz = (l > 0.f) ? 1.f / l : 0.f;
    const float avg = accw * invz;
    const float v0 = a0 * invz - avg * pos[r * 3 + 0];
    const float v1 = a1 * invz - avg * pos[r * 3 + 1];
    const float v2 = a2 * invz - avg * pos[r * 3 + 2];
    const float nrm = sqrtf(v0 * v0 + v1 * v1 + v2 * v2);
    const float invn = 1.f / fmaxf(nrm, 1e-12f);
    float4 o;
    o.x = v0 * invn; o.y = v1 * invn; o.z = v2 * invn; o.w = avg;
    *(float4*)(out + (size_t)r * (H_HEADS * 4) + h * 4) = o;
  }
}

// ---------------------------------------------------------------------------
extern "C" void kernel_launch(void* const* d_in, const int* in_sizes, int n_in,
                              void* d_out, int out_size, void* d_ws,
                              size_t ws_size, hipStream_t stream) {
  const float* x        = (const float*)d_in[0];
  const int* row_index  = (const int*)d_in[1];
  const int* col_index  = (const int*)d_in[2];
  const int* to_col     = (const int*)d_in[3];
  const float* att_bias = (const float*)d_in[4];
  const float* dist     = (const float*)d_in[5];
  const float* pos      = (const float*)d_in[6];
  const float* col_pos  = (const float*)d_in[7];
  const float* q_w      = (const float*)d_in[8];
  const float* q_b      = (const float*)d_in[9];
  const float* k_w      = (const float*)d_in[10];
  const float* k_b      = (const float*)d_in[11];
  float* out = (float*)d_out;

  // ws: q16[N*E s16] | k16[N*E s16] | logits[NNZ*H f32] | wq_s | wk_s
  //     | row_start[N+1] | ge[NNZ]
  short* q16 = (short*)d_ws;
  short* k16 = q16 + (size_t)N_NODES * E_DIM;
  float* logits = (float*)(k16 + (size_t)N_NODES * E_DIM);
  unsigned short* wq_s = (unsigned short*)(logits + (size_t)NNZ_E * H_HEADS);
  unsigned short* wk_s = wq_s + 512 * 1024;
  int* row_start = (int*)(wk_s + 512 * 1024);
  int* ge = row_start + (N_NODES + 1);

  prep_small<<<512 + NNZ_E / 256, 256, 0, stream>>>(
      q_w, k_w, row_index, col_index, to_col, wq_s, wk_s, row_start, ge);

  gemm_mfma<<<2048, 256, 0, stream>>>(x, wq_s, wk_s, q_b, k_b, q16, k16);

  edge_logits<<<NNZ_E / 16, 256, 0, stream>>>(q16, k16, row_index, ge,
                                              att_bias, logits);
  row_featurize<<<N_NODES / 4, 256, 0, stream>>>(logits, row_start, col_index,
                                                 dist, pos, col_pos, out);
}

// Round 14
// 340.464 us; speedup vs baseline: 1.3319x; 1.3319x over previous
//
#include <hip/hip_runtime.h>
#include <math.h>
#include <stdint.h>

#define N_NODES 32768
#define E_DIM   512
#define H_HEADS 8
#define D_HEAD  64
#define NNZ_E   524288

typedef __attribute__((ext_vector_type(4))) float f32x4;
typedef __attribute__((ext_vector_type(8))) short bf16x8;  // 8 bf16 = 4 VGPRs
typedef __attribute__((ext_vector_type(8))) short s16x8;

__device__ __forceinline__ unsigned short f32_to_bf16_rne(float f) {
  union { float f; uint32_t u; } v; v.f = f;
  const uint32_t u = v.u;
  return (unsigned short)((u + 0x7FFFu + ((u >> 16) & 1u)) >> 16);
}
__device__ __forceinline__ float bf16_to_f32(unsigned short h) {
  union { uint32_t u; float f; } v; v.u = ((uint32_t)h) << 16;
  return v.f;
}

// async 16B global->LDS (wave-uniform LDS base + lane*16)
__device__ __forceinline__ void async16(const void* g, void* l) {
  __builtin_amdgcn_global_load_lds(
      (const __attribute__((address_space(1))) void*)g,
      (__attribute__((address_space(3))) void*)l, 16, 0, 0);
}

// split pair (a,b) fp32 -> packed bf16 hi dword + packed bf16 lo dword.
__device__ __forceinline__ void split2(float a, float b,
                                       uint32_t& hi, uint32_t& lo) {
  const uint32_t ua = __float_as_uint(a), ub = __float_as_uint(b);
  hi = __builtin_amdgcn_perm(ub, ua, 0x07060302u);  // [b.hi16 : a.hi16]
  const float ra = a - __uint_as_float(ua & 0xFFFF0000u);
  const float rb = b - __uint_as_float(ub & 0xFFFF0000u);
  lo = __builtin_amdgcn_perm(__float_as_uint(rb), __float_as_uint(ra),
                             0x07060302u);
}

// ---------------------------------------------------------------------------
// prep_small: blocks 0..511 -> cvt_w (split q_w/k_w into bf16 hi|lo);
//             blocks 512..2559 -> build_aux (ge + CSR row_start).
// ---------------------------------------------------------------------------
__global__ __launch_bounds__(256) void prep_small(
    const float* __restrict__ q_w, const float* __restrict__ k_w,
    const int* __restrict__ row_index, const int* __restrict__ col_index,
    const int* __restrict__ to_col,
    unsigned short* __restrict__ wq_s, unsigned short* __restrict__ wk_s,
    int* __restrict__ row_start, int* __restrict__ ge) {
  const int b = blockIdx.x;
  if (b < 512) {
    const float* src = (b < 256) ? q_w : k_w;
    unsigned short* dst = (b < 256) ? wq_s : wk_s;
    const int t = (b & 255) * 256 + threadIdx.x;
    const int r = t >> 7;
    const int c4 = (t & 127) << 2;
    const float4 v = *(const float4*)(src + (size_t)r * 512 + c4);
    ushort4 hi, lo;
    hi.x = f32_to_bf16_rne(v.x); lo.x = f32_to_bf16_rne(v.x - bf16_to_f32(hi.x));
    hi.y = f32_to_bf16_rne(v.y); lo.y = f32_to_bf16_rne(v.y - bf16_to_f32(hi.y));
    hi.z = f32_to_bf16_rne(v.z); lo.z = f32_to_bf16_rne(v.z - bf16_to_f32(hi.z));
    hi.w = f32_to_bf16_rne(v.w); lo.w = f32_to_bf16_rne(v.w - bf16_to_f32(hi.w));
    *(ushort4*)(dst + (size_t)r * 1024 + c4) = hi;
    *(ushort4*)(dst + (size_t)r * 1024 + 512 + c4) = lo;
  } else {
    const int e = (b - 512) * 256 + threadIdx.x;
    if (e < NNZ_E) {
      ge[e] = to_col[col_index[e]];
      const int r0 = row_index[e];
      const int r1 = (e + 1 < NNZ_E) ? row_index[e + 1] : N_NODES;
      if (e == 0)
        for (int r = 0; r <= r0; ++r) row_start[r] = 0;
      for (int r = r0 + 1; r <= r1; ++r) row_start[r] = e + 1;
    }
  }
}

// ---------------------------------------------------------------------------
// Split-bf16 MFMA GEMM (r12 proven config). A staged RAW FP32 via
// global_load_lds, split hi/lo in-register (the LDS-free variant of r13
// regressed 2x: scattered fragment loads are transaction-bound; LDS staging
// is the coalescing device). XCD swizzle (b&7 = panel group) keeps the x
// panel HBM-once (FETCH 266->65 MB, measured r12). 3 terms = 48 MFMA per
// barrier pair; at 740 TF effective this sits at the m97-structure plateau.
// Outputs int16: q16 = q*16384, k16 = k*4096.
// ---------------------------------------------------------------------------
__global__ __launch_bounds__(256) void gemm_mfma(
    const float* __restrict__ x,             // [N][512] fp32
    const unsigned short* __restrict__ wqs,  // [512][1024] hi|lo
    const unsigned short* __restrict__ wks,
    const float* __restrict__ q_b, const float* __restrict__ k_b,
    short* __restrict__ q16, short* __restrict__ k16) {
  __shared__ float Af[128 * 32];          // 16 KB fp32 A tile
  __shared__ unsigned short Bh[128 * 32]; // 8 KB
  __shared__ unsigned short Bl[128 * 32]; // 8 KB
  const int tid = threadIdx.x;
  const int w = tid >> 6;        // wave 0..3
  const int l = tid & 63;

  const int b = blockIdx.x;
  const int j = b >> 3;
  const int mb = (b & 7) * 32 + (j >> 3);
  const int c = j & 7;
  const bool is_q = ((c & 1) == 0);
  const int bm = mb * 128;
  const int bn = (c >> 1) * 128;

  const unsigned short* __restrict__ wmat = is_q ? wqs : wks;
  const float* __restrict__ bias = is_q ? q_b : k_b;
  short* __restrict__ outp = is_q ? q16 : k16;
  const float oscale = is_q ? 2048.f : 4096.f;

  const int wm = (w & 1) * 64;   // wave's m-quadrant
  const int wn = (w >> 1) * 64;  // wave's n-quadrant

  f32x4 acc[4][4];
#pragma unroll
  for (int i = 0; i < 4; ++i)
#pragma unroll
    for (int jj = 0; jj < 4; ++jj) acc[i][jj] = (f32x4){0.f, 0.f, 0.f, 0.f};

  // A staging (fp32): lds chunk jx of row r holds global chunk jx^(r&7)
  const int ar = l >> 3;
  const int agc = (l & 7) ^ ar;
  // B staging (bf16 hi|lo, r7 swizzle)
  const int sr0 = w * 16 + (l >> 2);
  const int sr1 = sr0 + 64;
  const int sc = (((l & 3) ^ ((l >> 3) & 3)) << 3);
  // fragment maps
  const int fr = l & 15;
  const int fcs = ((((l >> 4) ^ ((fr >> 1) & 3)) & 3) << 3);
  const int akc = (l >> 4) * 2;
  const int as = l & 7;

  const unsigned short* __restrict__ wa = wmat + (size_t)bn * 1024;

  for (int k0 = 0; k0 < 512; k0 += 32) {
#pragma unroll
    for (int cc = 0; cc < 4; ++cc) {
      const int rbase = cc * 32 + w * 8;
      async16(x + (size_t)(bm + rbase + ar) * 512 + k0 + agc * 4,
              Af + rbase * 32);
    }
    async16(wa + (size_t)sr0 * 1024 + k0 + sc, Bh + w * 512);
    async16(wa + (size_t)sr1 * 1024 + k0 + sc, Bh + (w + 4) * 512);
    async16(wa + (size_t)sr0 * 1024 + 512 + k0 + sc, Bl + w * 512);
    async16(wa + (size_t)sr1 * 1024 + 512 + k0 + sc, Bl + (w + 4) * 512);
    __syncthreads();

    bf16x8 ahi[4], alo[4], bh[4];
#pragma unroll
    for (int i = 0; i < 4; ++i) {
      const int row = wm + i * 16 + fr;
      const float* rp = Af + row * 32;
      const float4 fa = *(const float4*)(rp + ((akc ^ as) << 2));
      const float4 fb = *(const float4*)(rp + (((akc + 1) ^ as) << 2));
      union { uint32_t u[4]; bf16x8 v; } ph, pl;
      split2(fa.x, fa.y, ph.u[0], pl.u[0]);
      split2(fa.z, fa.w, ph.u[1], pl.u[1]);
      split2(fb.x, fb.y, ph.u[2], pl.u[2]);
      split2(fb.z, fb.w, ph.u[3], pl.u[3]);
      ahi[i] = ph.v;
      alo[i] = pl.v;
    }
#pragma unroll
    for (int i = 0; i < 4; ++i)
      bh[i] = *(const bf16x8*)(Bh + (wn + i * 16 + fr) * 32 + fcs);
#pragma unroll
    for (int i = 0; i < 4; ++i)
#pragma unroll
      for (int jj = 0; jj < 4; ++jj)
        acc[i][jj] = __builtin_amdgcn_mfma_f32_16x16x32_bf16(
            ahi[i], bh[jj], acc[i][jj], 0, 0, 0);
#pragma unroll
    for (int i = 0; i < 4; ++i)
#pragma unroll
      for (int jj = 0; jj < 4; ++jj)
        acc[i][jj] = __builtin_amdgcn_mfma_f32_16x16x32_bf16(
            alo[i], bh[jj], acc[i][jj], 0, 0, 0);
#pragma unroll
    for (int jj = 0; jj < 4; ++jj)
      bh[jj] = *(const bf16x8*)(Bl + (wn + jj * 16 + fr) * 32 + fcs);
#pragma unroll
    for (int i = 0; i < 4; ++i)
#pragma unroll
      for (int jj = 0; jj < 4; ++jj)
        acc[i][jj] = __builtin_amdgcn_mfma_f32_16x16x32_bf16(
            ahi[i], bh[jj], acc[i][jj], 0, 0, 0);
    __syncthreads();
  }

  // epilogue: C/D layout col = l&15 (n), row = (l>>4)*4 + reg (m); int16 out
  const int cn = l & 15;
  const int cm4 = (l >> 4) * 4;
  float bvals[4];
#pragma unroll
  for (int jj = 0; jj < 4; ++jj) bvals[jj] = bias[bn + wn + jj * 16 + cn];
#pragma unroll
  for (int i = 0; i < 4; ++i) {
#pragma unroll
    for (int r = 0; r < 4; ++r) {
      const int m = bm + wm + i * 16 + cm4 + r;
      short* op = outp + (size_t)m * 512 + bn + wn + cn;
#pragma unroll
      for (int jj = 0; jj < 4; ++jj) {
        float v = (acc[i][jj][r] + bvals[jj]) * oscale;
        v = fmaxf(fminf(v, 32767.f), -32767.f);
        op[jj * 16] = (short)__float2int_rn(v);
      }
    }
  }
}

// ---------------------------------------------------------------------------
// Phase A: 4 edges per wave, batched loads; q AND k gathered as int16.
// logit = (sum q16*k16) / 2^26 + bias.
// ---------------------------------------------------------------------------
__global__ __launch_bounds__(256) void edge_logits(
    const short* __restrict__ q16, const short* __restrict__ k16,
    const int* __restrict__ row_index, const int* __restrict__ ge,
    const float* __restrict__ att_bias, float* __restrict__ logits) {
  const int wave = threadIdx.x >> 6;
  const int lane = threadIdx.x & 63;
  const int e0 = __builtin_amdgcn_readfirstlane((blockIdx.x * 4 + wave) * 4);

  int r[4], g[4];
#pragma unroll
  for (int i = 0; i < 4; ++i) {
    r[i] = row_index[e0 + i];
    g[i] = ge[e0 + i];
  }

  const int lo = lane * 8;
  s16x8 kv[4], qv[4];
#pragma unroll
  for (int i = 0; i < 4; ++i)
    kv[i] = *(const s16x8*)(k16 + (size_t)g[i] * E_DIM + lo);
#pragma unroll
  for (int i = 0; i < 4; ++i)
    qv[i] = *(const s16x8*)(q16 + (size_t)r[i] * E_DIM + lo);

  const int h = lane >> 3;
#pragma unroll
  for (int i = 0; i < 4; ++i) {
    float s = (float)qv[i][0] * (float)kv[i][0];
    s = fmaf((float)qv[i][1], (float)kv[i][1], s);
    s = fmaf((float)qv[i][2], (float)kv[i][2], s);
    s = fmaf((float)qv[i][3], (float)kv[i][3], s);
    s = fmaf((float)qv[i][4], (float)kv[i][4], s);
    s = fmaf((float)qv[i][5], (float)kv[i][5], s);
    s = fmaf((float)qv[i][6], (float)kv[i][6], s);
    s = fmaf((float)qv[i][7], (float)kv[i][7], s);
    s += __shfl_xor(s, 1);
    s += __shfl_xor(s, 2);
    s += __shfl_xor(s, 4);
    if ((lane & 7) == 0) {
      logits[(size_t)(e0 + i) * H_HEADS + h] =
          s * (1.f / 67108864.f) + att_bias[(size_t)h * NNZ_E + e0 + i];
    }
  }
}

// ---------------------------------------------------------------------------
// Phase B: 4 rows per block (1 wave per row); lane (h,j) strided
// online-softmax + 3-step merge.
// ---------------------------------------------------------------------------
__global__ __launch_bounds__(256) void row_featurize(
    const float* __restrict__ logits, const int* __restrict__ row_start,
    const int* __restrict__ col_index, const float* __restrict__ dist,
    const float* __restrict__ pos, const float* __restrict__ col_pos,
    float* __restrict__ out) {
  const int r = blockIdx.x * 4 + (threadIdx.x >> 6);
  const int lane = threadIdx.x & 63;
  const int h = lane >> 3;
  const int j = lane & 7;
  const int start = row_start[r];
  const int end = row_start[r + 1];

  float m = -INFINITY, l = 0.f, accw = 0.f, a0 = 0.f, a1 = 0.f, a2 = 0.f;

  for (int e = start + j; e < end; e += 8) {
    const float s = logits[(size_t)e * H_HEADS + h];
    const float dd = dist[e];
    const float w = (dd == 0.f) ? 0.f : 1.f / dd;
    const int c = col_index[e];
    const float nm = fmaxf(m, s);
    const float sc = __expf(m - nm);
    const float p = __expf(s - nm);
    m = nm;
    l = fmaf(l, sc, p);
    const float pw = p * w;
    accw = fmaf(accw, sc, pw);
    a0 = fmaf(a0, sc, pw * col_pos[c * 3 + 0]);
    a1 = fmaf(a1, sc, pw * col_pos[c * 3 + 1]);
    a2 = fmaf(a2, sc, pw * col_pos[c * 3 + 2]);
  }

#pragma unroll
  for (int off = 1; off < 8; off <<= 1) {
    const float mo = __shfl_xor(m, off);
    const float lo = __shfl_xor(l, off);
    const float wo = __shfl_xor(accw, off);
    const float b0 = __shfl_xor(a0, off);
    const float b1 = __shfl_xor(a1, off);
    const float b2 = __shfl_xor(a2, off);
    const float nm = fmaxf(m, mo);
    const float s1 = __expf(fmaxf(m - nm, -80.f));  // NaN (inf-inf) -> -80
    const float s2 = __expf(fmaxf(mo - nm, -80.f));
    m = nm;
    l = l * s1 + lo * s2;
    accw = accw * s1 + wo * s2;
    a0 = a0 * s1 + b0 * s2;
    a1 = a1 * s1 + b1 * s2;
    a2 = a2 * s1 + b2 * s2;
  }

  if (j == 0) {
    const float invz = (l > 0.f) ? 1.f / l : 0.f;
    const float avg = accw * invz;
    const float v0 = a0 * invz - avg * pos[r * 3 + 0];
    const float v1 = a1 * invz - avg * pos[r * 3 + 1];
    const float v2 = a2 * invz - avg * pos[r * 3 + 2];
    const float nrm = sqrtf(v0 * v0 + v1 * v1 + v2 * v2);
    const float invn = 1.f / fmaxf(nrm, 1e-12f);
    float4 o;
    o.x = v0 * invn; o.y = v1 * invn; o.z = v2 * invn; o.w = avg;
    *(float4*)(out + (size_t)r * (H_HEADS * 4) + h * 4) = o;
  }
}

// ---------------------------------------------------------------------------
extern "C" void kernel_launch(void* const* d_in, const int* in_sizes, int n_in,
                              void* d_out, int out_size, void* d_ws,
                              size_t ws_size, hipStream_t stream) {
  const float* x        = (const float*)d_in[0];
  const int* row_index  = (const int*)d_in[1];
  const int* col_index  = (const int*)d_in[2];
  const int* to_col     = (const int*)d_in[3];
  const float* att_bias = (const float*)d_in[4];
  const float* dist     = (const float*)d_in[5];
  const float* pos      = (const float*)d_in[6];
  const float* col_pos  = (const float*)d_in[7];
  const float* q_w      = (const float*)d_in[8];
  const float* q_b      = (const float*)d_in[9];
  const float* k_w      = (const float*)d_in[10];
  const float* k_b      = (const float*)d_in[11];
  float* out = (float*)d_out;

  // ws: q16[N*E s16] | k16[N*E s16] | logits[NNZ*H f32] | wq_s | wk_s
  //     | row_start[N+1] | ge[NNZ]
  short* q16 = (short*)d_ws;
  short* k16 = q16 + (size_t)N_NODES * E_DIM;
  float* logits = (float*)(k16 + (size_t)N_NODES * E_DIM);
  unsigned short* wq_s = (unsigned short*)(logits + (size_t)NNZ_E * H_HEADS);
  unsigned short* wk_s = wq_s + 512 * 1024;
  int* row_start = (int*)(wk_s + 512 * 1024);
  int* ge = row_start + (N_NODES + 1);

  prep_small<<<512 + NNZ_E / 256, 256, 0, stream>>>(
      q_w, k_w, row_index, col_index, to_col, wq_s, wk_s, row_start, ge);

  gemm_mfma<<<2048, 256, 0, stream>>>(x, wq_s, wk_s, q_b, k_b, q16, k16);

  edge_logits<<<NNZ_E / 16, 256, 0, stream>>>(q16, k16, row_index, ge,
                                              att_bias, logits);
  row_featurize<<<N_NODES / 4, 256, 0, stream>>>(logits, row_start, col_index,
                                                 dist, pos, col_pos, out);
}